// Round 3
// baseline (209.974 us; speedup 1.0000x reference)
//
#include <hip/hip_runtime.h>
#include <math.h>

// MultiHeadedAttention: B=8, d_model=256, H=4, d_head=64, N=2048, fp32 I/O.
// Round 9: attn async pipeline — 3 LDS buffers, raw s_barrier + counted
// s_waitcnt vmcnt(4) (never drain to 0 in-loop), so prefetch loads stay in
// flight across barriers (T3/T4). WAR-safe: STAGE(t+1) writes the buffer
// last read at t-2, two barriers apart. s_setprio(1) around MFMA clusters
// (T5). Rowsum via v_dot2_f32_f16 on packed P (consistent with f16 PV).
// Channel trap: reshape(b,64,4,N) => c = 4*d + h (heads fast).

constexpr int BATCH  = 8;
constexpr int DMODEL = 256;
constexpr int SEQ    = 2048;
constexpr int HDIM   = 64;
constexpr int TN     = 128;        // attn q rows per block (32/wave)
constexpr int TM     = 64;         // attn j per tile
constexpr int NJT    = SEQ / TM;   // 32

typedef _Float16 half2_t __attribute__((ext_vector_type(2)));
typedef _Float16 half4_t __attribute__((ext_vector_type(4)));
typedef _Float16 half8_t __attribute__((ext_vector_type(8)));
typedef float    float4_t __attribute__((ext_vector_type(4)));

static __device__ __forceinline__ void ld16_lds(const void* g, void* l) {
    __builtin_amdgcn_global_load_lds(
        (const __attribute__((address_space(1))) unsigned*)g,
        (__attribute__((address_space(3))) unsigned*)l, 16, 0, 0);
}

// ---------- k0: weights fp32 -> f16 ----------
__global__ __launch_bounds__(256)
void prep_w(const float* __restrict__ Wq, const float* __restrict__ Wk,
            const float* __restrict__ Wv, const float* __restrict__ Wm,
            _Float16* __restrict__ wf)
{
    const int which = blockIdx.y;
    const float* src = which == 0 ? Wq : which == 1 ? Wk : which == 2 ? Wv : Wm;
    const int i = (blockIdx.x * 256 + threadIdx.x) * 4;
    const float4 v = *(const float4*)&src[i];
    half4_t o; o[0] = v.x; o[1] = v.y; o[2] = v.z; o[3] = v.w;
    *(half4_t*)&wf[(size_t)which * DMODEL * DMODEL + i] = o;
}

// ---------- k1: fused transpose + QKV projection ----------
// grid (SEQ/64=32, 3*BATCH=24), 256 thr, 4 waves (wave w -> co w*64..+63).
// Stage A: X[b,c,n] fp32 -> LDS Xs[n][c] f16 (via proven [64][65] fp32 tile).
// Stage B: D[co][n] = sum_ci W[co][ci] Xs[n][ci], MFMA, W from L2.
// Epilogues: q/k -> [bh][n][d], chunk at dc ^ ((n&3)|((n>>3&1)<<2));
// v -> 8KB j-tiles, chunk jc at jc^(d&7). Q gets * 0.125*log2(e) folded in.
__global__ __launch_bounds__(256, 3)
void gemm_qkv(const _Float16* __restrict__ wf, const float* __restrict__ bq,
              const float* __restrict__ bk, const float* __restrict__ bv,
              const float* __restrict__ Xq, const float* __restrict__ Xk,
              const float* __restrict__ Xv, _Float16* __restrict__ qT,
              _Float16* __restrict__ kT, _Float16* __restrict__ vT)
{
    const int n0 = blockIdx.x * 64;
    const int proj = blockIdx.y >> 3, b = blockIdx.y & 7;
    const _Float16* W    = wf + (size_t)proj * DMODEL * DMODEL;
    const float*    bias = proj == 0 ? bq : proj == 1 ? bk : bv;
    const float*    X    = (proj == 0 ? Xq : proj == 1 ? Xk : Xv)
                           + (size_t)b * DMODEL * SEQ;
    // fold attention scale (1/8) and log2(e) into Q so attn uses exp2 directly
    const float qs = (proj == 0) ? 0.18033688011112042f : 1.0f;

    __shared__ __align__(16) char lds[50432];
    float*    T  = (float*)lds;               // [64][65] fp32 (stage A scratch)
    _Float16* Xs = (_Float16*)(lds + 16640);  // [64][264] f16
    _Float16* Tw = (_Float16*)lds;            // [4][64][68] f16 (epilogue, aliases)

    const int tid = threadIdx.x, tn = tid & 15, tc = tid >> 4;

    // ---- Stage A: transpose+cvt 256ci x 64n ----
    #pragma unroll
    for (int cc = 0; cc < 4; ++cc) {
        __syncthreads();
        #pragma unroll
        for (int i = 0; i < 4; ++i) {
            const int c = tc + 16 * i;
            const float4 v = *(const float4*)&X[(size_t)(cc * 64 + c) * SEQ + n0 + tn * 4];
            T[c * 65 + tn * 4 + 0] = v.x; T[c * 65 + tn * 4 + 1] = v.y;
            T[c * 65 + tn * 4 + 2] = v.z; T[c * 65 + tn * 4 + 3] = v.w;
        }
        __syncthreads();
        #pragma unroll
        for (int i = 0; i < 4; ++i) {
            const int n = tc + 16 * i;
            half4_t h4;
            #pragma unroll
            for (int j = 0; j < 4; ++j) h4[j] = (_Float16)T[(tn * 4 + j) * 65 + n];
            *(half4_t*)&Xs[n * 264 + cc * 64 + tn * 4] = h4;
        }
    }
    __syncthreads();

    // ---- Stage B: MFMA GEMM ----
    const int w = tid >> 6, lane = tid & 63;
    const int lm = lane & 15, g = lane >> 4, g8 = g * 8;
    const int cw0 = w * 64;

    float4_t acc[4][4];
    #pragma unroll
    for (int mt = 0; mt < 4; ++mt)
        #pragma unroll
        for (int nt = 0; nt < 4; ++nt) acc[mt][nt] = (float4_t){0.f, 0.f, 0.f, 0.f};

    #pragma unroll
    for (int k0 = 0; k0 < DMODEL; k0 += 64) {
        half8_t a[4][2], bb[4][2];
        #pragma unroll
        for (int mt = 0; mt < 4; ++mt)
            #pragma unroll
            for (int kd = 0; kd < 2; ++kd)
                a[mt][kd] = *(const half8_t*)&W[(size_t)(cw0 + mt * 16 + lm) * DMODEL
                                                + k0 + kd * 32 + g8];
        #pragma unroll
        for (int nt = 0; nt < 4; ++nt)
            #pragma unroll
            for (int kd = 0; kd < 2; ++kd)
                bb[nt][kd] = *(const half8_t*)&Xs[(nt * 16 + lm) * 264
                                                  + k0 + kd * 32 + g8];
        #pragma unroll
        for (int kd = 0; kd < 2; ++kd)
            #pragma unroll
            for (int mt = 0; mt < 4; ++mt)
                #pragma unroll
                for (int nt = 0; nt < 4; ++nt)
                    acc[mt][nt] = __builtin_amdgcn_mfma_f32_16x16x32_f16(
                        a[mt][kd], bb[nt][kd], acc[mt][nt], 0, 0, 0);
    }
    __syncthreads();   // Xs dead; Tw may now alias it

    // wave-private transpose: Tw[w][n_local][co_local]
    #pragma unroll
    for (int mt = 0; mt < 4; ++mt) {
        const float4 b4 = *(const float4*)&bias[cw0 + mt * 16 + g * 4];
        const float bb4[4] = {b4.x, b4.y, b4.z, b4.w};
        #pragma unroll
        for (int nt = 0; nt < 4; ++nt) {
            half4_t pk;
            #pragma unroll
            for (int r = 0; r < 4; ++r)
                pk[r] = (_Float16)((acc[mt][nt][r] + bb4[r]) * qs);
            *(half4_t*)&Tw[((w * 64 + nt * 16 + lm)) * 68 + mt * 16 + g * 4] = pk;
        }
    }

    if (proj < 2) {
        // q/k: [bh][n][d], 16B chunk at ((w*2+dc) ^ ((n&3)|((n>>3&1)<<2)))
        _Float16* dst = (proj == 0 ? qT : kT);
        const int h2 = lane >> 4, lml = lane & 15;
        #pragma unroll
        for (int it = 0; it < 4; ++it) {
            const int nl = it * 16 + lml;
            const int hs = (nl & 3) | (((nl >> 3) & 1) << 2);
            #pragma unroll
            for (int dc = 0; dc < 2; ++dc) {
                half8_t ch;
                #pragma unroll
                for (int e = 0; e < 8; ++e)
                    ch[e] = Tw[(w * 64 + nl) * 68 + 4 * (dc * 8 + e) + h2];
                const int chunk = (w * 2 + dc) ^ hs;
                *(half8_t*)&dst[((size_t)(b * 4 + h2) * SEQ + n0 + nl) * HDIM
                                + chunk * 8] = ch;
            }
        }
    } else {
        // v: tiles [bh][jt][d][jl], 16B chunk jc at jc^(d&7)
        const int hh = lane & 3, dl = (lane >> 2) & 15;
        const int d = w * 16 + dl;
        const size_t rowbase =
            (((size_t)(b * 4 + hh) * NJT + (n0 >> 6)) * HDIM + d) * (size_t)TM;
        #pragma unroll
        for (int jc = 0; jc < 8; ++jc) {
            half8_t ch;
            #pragma unroll
            for (int e = 0; e < 8; ++e)
                ch[e] = Tw[(w * 64 + jc * 8 + e) * 68 + 4 * dl + hh];
            *(half8_t*)&vT[rowbase + ((jc ^ (dl & 7)) << 3)] = ch;
        }
    }
}

// ---------- k2: attention, split-j, async-pipelined ----------
// grid 1024 flat; XCD-aware remap: work = (lid&7)*128 + (lid>>3).
// 4 waves x 32 rows. 16 j-tiles. QK^T with permuted K rows; PV via
// mfma_16x16x32. 3-buffer LDS pipeline: STAGE(t+1) -> vmcnt(4) -> raw
// s_barrier -> compute(t). Prefetch spans the barrier (no vmcnt(0) drain).
// Q pre-scaled by 0.125*log2(e) -> P = exp2(S).
__global__ __launch_bounds__(256, 3)
void attn_f16(const _Float16* __restrict__ qT, const _Float16* __restrict__ kT,
              const _Float16* __restrict__ vT, _Float16* __restrict__ xa,
              _Float16* __restrict__ xb, float* __restrict__ rs)
{
    const int lid = blockIdx.x;
    const int work = (lid & 7) * 128 + (lid >> 3);
    const int bh = work >> 5, b = bh >> 2, h = bh & 3;
    const int jh = (work >> 4) & 1;
    const int ib = work & 15;
    const int tid = threadIdx.x, wid = tid >> 6, lane = tid & 63;
    const int lm = lane & 15, g = lane >> 4;
    const int i0 = ib * TN + wid * 32;

    __shared__ _Float16 Kb[3][TM * HDIM];   // 8 KB each, 48 KB total
    __shared__ _Float16 Vb[3][TM * HDIM];

    const int hq = (lm & 3) | (((lm >> 3) & 1) << 2);  // Q-row hash (row%16=lm)
    const int hk = (lm & 3) | (((lm >> 2) & 1) << 2);  // permuted K-row hash
    const int rbase = 8 * (lm >> 2) + (lm & 3);        // K row permutation

    // Q B-frags (scale pre-folded)
    half8_t bq[2][2];
    const _Float16* qbase = qT + (size_t)bh * SEQ * HDIM;
    #pragma unroll
    for (int rt = 0; rt < 2; ++rt)
        #pragma unroll
        for (int kd = 0; kd < 2; ++kd) {
            const int row = i0 + rt * 16 + lm;
            bq[rt][kd] = *(const half8_t*)(qbase + (size_t)row * HDIM
                                           + (((kd * 4 + g) ^ hq) << 3));
        }

    const char* kt = (const char*)(kT + ((size_t)bh * SEQ + jh * (SEQ / 2)) * HDIM);
    const char* vt = (const char*)(vT + ((size_t)bh * NJT + jh * 16) * TM * HDIM);

    float4_t o[2][4];
    float rsum[2][2] = {{0.f, 0.f}, {0.f, 0.f}};   // [jb][rt]
    #pragma unroll
    for (int rt = 0; rt < 2; ++rt)
        #pragma unroll
        for (int dt = 0; dt < 4; ++dt) o[rt][dt] = (float4_t){0.f, 0.f, 0.f, 0.f};

    const half2_t one2 = {(_Float16)1.f, (_Float16)1.f};

    #define STAGE(jt, bu)                                                     \
        {                                                                     \
            const char* kg = kt + (size_t)(jt) * 8192;                        \
            const char* vg = vt + (size_t)(jt) * 8192;                        \
            _Pragma("unroll")                                                 \
            for (int p = 0; p < 2; ++p) {                                     \
                const int c = wid + p * 4;                                    \
                ld16_lds(kg + c * 1024 + lane * 16, (char*)&Kb[bu][0] + c * 1024); \
                ld16_lds(vg + c * 1024 + lane * 16, (char*)&Vb[bu][0] + c * 1024); \
            }                                                                 \
        }

    STAGE(0, 0);

    int cur = 0;
    #pragma unroll
    for (int jt = 0; jt < 16; ++jt) {
        const int nxt = (cur == 2) ? 0 : cur + 1;
        if (jt + 1 < 16) {
            STAGE(jt + 1, nxt);
            // wait only for tile-jt's 4 loads (issued one iteration ago);
            // the 4 just-issued prefetch loads stay in flight across the barrier
            asm volatile("s_waitcnt vmcnt(4)" ::: "memory");
        } else {
            asm volatile("s_waitcnt vmcnt(0)" ::: "memory");
        }
        __builtin_amdgcn_s_barrier();
        asm volatile("" ::: "memory");   // keep ds_reads below the barrier

        // S^T = K·Q^T with permuted K rows: s[jb][u][rt], lane g reg r holds
        // S^T[j = jb*32 + 8g + 4u + r][i = rt*16 + lm]
        float4_t s[2][2][2];
        #pragma unroll
        for (int jb = 0; jb < 2; ++jb)
            #pragma unroll
            for (int u = 0; u < 2; ++u)
                #pragma unroll
                for (int rt = 0; rt < 2; ++rt)
                    s[jb][u][rt] = (float4_t){0.f, 0.f, 0.f, 0.f};
        __builtin_amdgcn_s_setprio(1);
        #pragma unroll
        for (int kd = 0; kd < 2; ++kd)
            #pragma unroll
            for (int jb = 0; jb < 2; ++jb)
                #pragma unroll
                for (int u = 0; u < 2; ++u) {
                    const int jrow = jb * 32 + rbase + 4 * u;
                    const half8_t fk = *(const half8_t*)
                        &Kb[cur][jrow * HDIM + (((kd * 4 + g) ^ hk) << 3)];
                    #pragma unroll
                    for (int rt = 0; rt < 2; ++rt)
                        s[jb][u][rt] = __builtin_amdgcn_mfma_f32_16x16x32_f16(
                            fk, bq[rt][kd], s[jb][u][rt], 0, 0, 0);
                }
        __builtin_amdgcn_s_setprio(0);

        // P = exp2(S); pack u=0 -> e0..3, u=1 -> e4..7 (j = 8g+e per lane);
        // rowsum via dot2 on the packed f16 P (consistent with PV operand)
        half8_t ap[2][2];
        #pragma unroll
        for (int jb = 0; jb < 2; ++jb)
            #pragma unroll
            for (int rt = 0; rt < 2; ++rt) {
                half8_t p;
                #pragma unroll
                for (int r = 0; r < 4; ++r) {
                    p[r]     = (_Float16)__builtin_amdgcn_exp2f(s[jb][0][rt][r]);
                    p[r + 4] = (_Float16)__builtin_amdgcn_exp2f(s[jb][1][rt][r]);
                }
                ap[jb][rt] = p;
                #pragma unroll
                for (int q = 0; q < 4; ++q) {
                    half2_t h2; h2[0] = p[2 * q]; h2[1] = p[2 * q + 1];
                    rsum[jb][rt] = __builtin_amdgcn_fdot2(h2, one2,
                                                          rsum[jb][rt], false);
                }
            }

        // O += P·V, x32 MFMA, V as b128 reads (chunk (jb*4+g)^(lm&7))
        __builtin_amdgcn_s_setprio(1);
        #pragma unroll
        for (int jb = 0; jb < 2; ++jb)
            #pragma unroll
            for (int dt = 0; dt < 4; ++dt) {
                const int d = dt * 16 + lm;
                const half8_t fv = *(const half8_t*)
                    &Vb[cur][d * TM + (((jb * 4 + g) ^ (lm & 7)) << 3)];
                #pragma unroll
                for (int rt = 0; rt < 2; ++rt)
                    o[rt][dt] = __builtin_amdgcn_mfma_f32_16x16x32_f16(
                        ap[jb][rt], fv, o[rt][dt], 0, 0, 0);
            }
        __builtin_amdgcn_s_setprio(0);
        cur = nxt;
    }

    // epilogue: unnormalized O -> xp[b][n][c]; rowsum reduce -> rs[jh][bh][n]
    _Float16* xp = jh ? xb : xa;
    #pragma unroll
    for (int rt = 0; rt < 2; ++rt)
        #pragma unroll
        for (int dt = 0; dt < 4; ++dt) {
            const int c = 4 * (dt * 16 + lm) + h;
            #pragma unroll
            for (int r = 0; r < 4; ++r) {
                const int n = i0 + rt * 16 + 4 * g + r;
                xp[((size_t)b * SEQ + n) * DMODEL + c] = (_Float16)o[rt][dt][r];
            }
        }
    #pragma unroll
    for (int rt = 0; rt < 2; ++rt) {
        float v = rsum[0][rt] + rsum[1][rt];
        v += __shfl_xor(v, 16);
        v += __shfl_xor(v, 32);
        if (g == 0)
            rs[((size_t)jh * 32 + bh) * SEQ + i0 + rt * 16 + lm] = v;
    }
    #undef STAGE
}

// ---------- k3: final projection with fused combine/normalize ----------
// B-frag = (xa + xb) * inv[h(n)] (packed f16), then MFMA with Wm. fp32 out.
__global__ __launch_bounds__(256)
void gemm_final(const _Float16* __restrict__ wm, const float* __restrict__ bias,
                const _Float16* __restrict__ xa, const _Float16* __restrict__ xb,
                const float* __restrict__ rs, float* __restrict__ out)
{
    const int n0 = blockIdx.x * 64, m0 = blockIdx.y * 128;
    const int b = blockIdx.z;
    const int tid = threadIdx.x, w = tid >> 6, lane = tid & 63;
    const int lm = lane & 15, g = lane >> 4, g8 = g * 8;
    const int cw0 = m0 + w * 32;

    const _Float16* Xa = xa + ((size_t)b * SEQ + n0) * DMODEL;
    const _Float16* Xb2 = xb + ((size_t)b * SEQ + n0) * DMODEL;

    // per-nt packed normalizers: pm[nt][e] = 1/(rsA+rsB) for h = e&3 at n
    half8_t pm[4];
    #pragma unroll
    for (int nt = 0; nt < 4; ++nt) {
        const int n = n0 + nt * 16 + lm;
        #pragma unroll
        for (int hh = 0; hh < 4; ++hh) {
            const float l = rs[(size_t)(b * 4 + hh) * SEQ + n]
                          + rs[(size_t)(32 + b * 4 + hh) * SEQ + n];
            const _Float16 iv = (_Float16)(1.0f / l);
            pm[nt][hh] = iv; pm[nt][hh + 4] = iv;
        }
    }

    float4_t acc[2][4];
    #pragma unroll
    for (int mt = 0; mt < 2; ++mt)
        #pragma unroll
        for (int nt = 0; nt < 4; ++nt) acc[mt][nt] = (float4_t){0.f, 0.f, 0.f, 0.f};

    #pragma unroll
    for (int k0 = 0; k0 < DMODEL; k0 += 64) {
        half8_t a[2][2], bb[4][2];
        #pragma unroll
        for (int mt = 0; mt < 2; ++mt)
            #pragma unroll
            for (int kd = 0; kd < 2; ++kd)
                a[mt][kd] = *(const half8_t*)&wm[(size_t)(cw0 + mt * 16 + lm) * DMODEL
                                                 + k0 + kd * 32 + g8];
        #pragma unroll
        for (int nt = 0; nt < 4; ++nt)
            #pragma unroll
            for (int kd = 0; kd < 2; ++kd) {
                const size_t off = (size_t)(nt * 16 + lm) * DMODEL + k0 + kd * 32 + g8;
                const half8_t va = *(const half8_t*)&Xa[off];
                const half8_t vb = *(const half8_t*)&Xb2[off];
                bb[nt][kd] = (va + vb) * pm[nt];
            }
        #pragma unroll
        for (int kd = 0; kd < 2; ++kd)
            #pragma unroll
            for (int mt = 0; mt < 2; ++mt)
                #pragma unroll
                for (int nt = 0; nt < 4; ++nt)
                    acc[mt][nt] = __builtin_amdgcn_mfma_f32_16x16x32_f16(
                        a[mt][kd], bb[nt][kd], acc[mt][nt], 0, 0, 0);
    }

    #pragma unroll
    for (int mt = 0; mt < 2; ++mt)
        #pragma unroll
        for (int r = 0; r < 4; ++r) {
            const int co = cw0 + mt * 16 + g * 4 + r;
            const float bv_ = bias[co];
            #pragma unroll
            for (int nt = 0; nt < 4; ++nt)
                out[((size_t)b * DMODEL + co) * SEQ + n0 + nt * 16 + lm] =
                    acc[mt][nt][r] + bv_;
        }
}

extern "C" void kernel_launch(void* const* d_in, const int* in_sizes, int n_in,
                              void* d_out, int out_size, void* d_ws, size_t ws_size,
                              hipStream_t stream) {
    const float* query = (const float*)d_in[0];
    const float* key_  = (const float*)d_in[1];
    const float* value = (const float*)d_in[2];
    const float* Wq = (const float*)d_in[3];  const float* bq = (const float*)d_in[4];
    const float* Wk = (const float*)d_in[5];  const float* bk = (const float*)d_in[6];
    const float* Wv = (const float*)d_in[7];  const float* bv = (const float*)d_in[8];
    const float* Wm = (const float*)d_in[9];  const float* bm = (const float*)d_in[10];
    float* out = (float*)d_out;

    const size_t bufElems = (size_t)BATCH * DMODEL * SEQ;   // 4,194,304
    _Float16* qT = (_Float16*)d_ws;    // 8 MB [bh][n][d] swizzled
    _Float16* kT = qT + bufElems;      // 8 MB
    _Float16* vT = kT + bufElems;      // 8 MB [bh][jt][d][jl] swizzled
    _Float16* xa = vT + bufElems;      // 8 MB [b][n][c] unnormalized, j-half 0
    _Float16* xb = xa + bufElems;      // 8 MB j-half 1
    _Float16* wf = xb + bufElems;      // 512 KB f16 weights
    float*    rsb = (float*)(wf + 4 * DMODEL * DMODEL);  // 512 KB rowsums [2][32][2048]

    prep_w<<<dim3(DMODEL * DMODEL / 1024, 4), 256, 0, stream>>>(Wq, Wk, Wv, Wm, wf);
    gemm_qkv<<<dim3(SEQ / 64, 3 * BATCH), 256, 0, stream>>>(
        wf, bq, bk, bv, query, key_, value, qT, kT, vT);
    attn_f16<<<dim3(1024), 256, 0, stream>>>(qT, kT, vT, xa, xb, rsb);
    gemm_final<<<dim3(SEQ / 64, 2, BATCH), 256, 0, stream>>>(
        wf + (size_t)3 * DMODEL * DMODEL, bm, xa, xb, rsb, out);
}

// Round 4
// 185.662 us; speedup vs baseline: 1.1309x; 1.1309x over previous
//
#include <hip/hip_runtime.h>
#include <math.h>

// MultiHeadedAttention: B=8, d_model=256, H=4, d_head=64, N=2048, fp32 I/O.
// Round 10: REVERT attn to round-8 (async pipeline regressed: phase-locked
// blocks were load-bearing for L2 write-merge + K/V reuse). Attack the
// unseen 141us of non-attn time: prep_w dispatch deleted (GEMMs cvt fp32
// weights in-register, RNE), gemm_final LDS-stages (xa+xb) once per block
// (was 4x redundant global reads per wave).
// Channel trap: reshape(b,64,4,N) => c = 4*d + h (heads fast).

constexpr int BATCH  = 8;
constexpr int DMODEL = 256;
constexpr int SEQ    = 2048;
constexpr int HDIM   = 64;
constexpr int TN     = 128;        // attn q rows per block (32/wave)
constexpr int TM     = 64;         // attn j per tile
constexpr int NJT    = SEQ / TM;   // 32

typedef _Float16 half2_t __attribute__((ext_vector_type(2)));
typedef _Float16 half4_t __attribute__((ext_vector_type(4)));
typedef _Float16 half8_t __attribute__((ext_vector_type(8)));
typedef float    float4_t __attribute__((ext_vector_type(4)));

static __device__ __forceinline__ void ld16_lds(const void* g, void* l) {
    __builtin_amdgcn_global_load_lds(
        (const __attribute__((address_space(1))) unsigned*)g,
        (__attribute__((address_space(3))) unsigned*)l, 16, 0, 0);
}

// fp32x8 -> half8 (RNE, same numerics as the old prep_w path)
static __device__ __forceinline__ half8_t cvt8(const float4 w0, const float4 w1) {
    half8_t a;
    a[0] = (_Float16)w0.x; a[1] = (_Float16)w0.y;
    a[2] = (_Float16)w0.z; a[3] = (_Float16)w0.w;
    a[4] = (_Float16)w1.x; a[5] = (_Float16)w1.y;
    a[6] = (_Float16)w1.z; a[7] = (_Float16)w1.w;
    return a;
}

// ---------- k1: fused transpose + QKV projection ----------
// grid (SEQ/64=32, 3*BATCH=24), 256 thr, 4 waves (wave w -> co w*64..+63).
// Stage A: X[b,c,n] fp32 -> LDS Xs[n][c] f16 (via proven [64][65] fp32 tile).
// Stage B: D[co][n] = sum_ci W[co][ci] Xs[n][ci]; A-frags read fp32 from L2
// and cvt'd in-register (prep_w dispatch eliminated).
// Epilogues: q/k -> [bh][n][d], chunk at dc ^ ((n&3)|((n>>3&1)<<2));
// v -> 8KB j-tiles, chunk jc at jc^(d&7). Q gets * 0.125*log2(e) folded in.
__global__ __launch_bounds__(256, 3)
void gemm_qkv(const float* __restrict__ Wq, const float* __restrict__ Wk,
              const float* __restrict__ Wv,
              const float* __restrict__ bq, const float* __restrict__ bk,
              const float* __restrict__ bv,
              const float* __restrict__ Xq, const float* __restrict__ Xk,
              const float* __restrict__ Xv, _Float16* __restrict__ qT,
              _Float16* __restrict__ kT, _Float16* __restrict__ vT)
{
    const int n0 = blockIdx.x * 64;
    const int proj = blockIdx.y >> 3, b = blockIdx.y & 7;
    const float* W    = proj == 0 ? Wq : proj == 1 ? Wk : Wv;   // fp32 [co][ci]
    const float* bias = proj == 0 ? bq : proj == 1 ? bk : bv;
    const float* X    = (proj == 0 ? Xq : proj == 1 ? Xk : Xv)
                        + (size_t)b * DMODEL * SEQ;
    // fold attention scale (1/8) and log2(e) into Q so attn uses exp2 directly
    const float qs = (proj == 0) ? 0.18033688011112042f : 1.0f;

    __shared__ __align__(16) char lds[50432];
    float*    T  = (float*)lds;               // [64][65] fp32 (stage A scratch)
    _Float16* Xs = (_Float16*)(lds + 16640);  // [64][264] f16
    _Float16* Tw = (_Float16*)lds;            // [4][64][68] f16 (epilogue, aliases)

    const int tid = threadIdx.x, tn = tid & 15, tc = tid >> 4;

    // ---- Stage A: transpose+cvt 256ci x 64n ----
    #pragma unroll
    for (int cc = 0; cc < 4; ++cc) {
        __syncthreads();
        #pragma unroll
        for (int i = 0; i < 4; ++i) {
            const int c = tc + 16 * i;
            const float4 v = *(const float4*)&X[(size_t)(cc * 64 + c) * SEQ + n0 + tn * 4];
            T[c * 65 + tn * 4 + 0] = v.x; T[c * 65 + tn * 4 + 1] = v.y;
            T[c * 65 + tn * 4 + 2] = v.z; T[c * 65 + tn * 4 + 3] = v.w;
        }
        __syncthreads();
        #pragma unroll
        for (int i = 0; i < 4; ++i) {
            const int n = tc + 16 * i;
            half4_t h4;
            #pragma unroll
            for (int j = 0; j < 4; ++j) h4[j] = (_Float16)T[(tn * 4 + j) * 65 + n];
            *(half4_t*)&Xs[n * 264 + cc * 64 + tn * 4] = h4;
        }
    }
    __syncthreads();

    // ---- Stage B: MFMA GEMM ----
    const int w = tid >> 6, lane = tid & 63;
    const int lm = lane & 15, g = lane >> 4, g8 = g * 8;
    const int cw0 = w * 64;

    float4_t acc[4][4];
    #pragma unroll
    for (int mt = 0; mt < 4; ++mt)
        #pragma unroll
        for (int nt = 0; nt < 4; ++nt) acc[mt][nt] = (float4_t){0.f, 0.f, 0.f, 0.f};

    #pragma unroll
    for (int k0 = 0; k0 < DMODEL; k0 += 64) {
        half8_t a[4][2], bb[4][2];
        #pragma unroll
        for (int mt = 0; mt < 4; ++mt)
            #pragma unroll
            for (int kd = 0; kd < 2; ++kd) {
                const float* wp = &W[(size_t)(cw0 + mt * 16 + lm) * DMODEL
                                     + k0 + kd * 32 + g8];
                a[mt][kd] = cvt8(*(const float4*)wp, *(const float4*)(wp + 4));
            }
        #pragma unroll
        for (int nt = 0; nt < 4; ++nt)
            #pragma unroll
            for (int kd = 0; kd < 2; ++kd)
                bb[nt][kd] = *(const half8_t*)&Xs[(nt * 16 + lm) * 264
                                                  + k0 + kd * 32 + g8];
        #pragma unroll
        for (int kd = 0; kd < 2; ++kd)
            #pragma unroll
            for (int mt = 0; mt < 4; ++mt)
                #pragma unroll
                for (int nt = 0; nt < 4; ++nt)
                    acc[mt][nt] = __builtin_amdgcn_mfma_f32_16x16x32_f16(
                        a[mt][kd], bb[nt][kd], acc[mt][nt], 0, 0, 0);
    }
    __syncthreads();   // Xs dead; Tw may now alias it

    // wave-private transpose: Tw[w][n_local][co_local]
    #pragma unroll
    for (int mt = 0; mt < 4; ++mt) {
        const float4 b4 = *(const float4*)&bias[cw0 + mt * 16 + g * 4];
        const float bb4[4] = {b4.x, b4.y, b4.z, b4.w};
        #pragma unroll
        for (int nt = 0; nt < 4; ++nt) {
            half4_t pk;
            #pragma unroll
            for (int r = 0; r < 4; ++r)
                pk[r] = (_Float16)((acc[mt][nt][r] + bb4[r]) * qs);
            *(half4_t*)&Tw[((w * 64 + nt * 16 + lm)) * 68 + mt * 16 + g * 4] = pk;
        }
    }

    if (proj < 2) {
        // q/k: [bh][n][d], 16B chunk at ((w*2+dc) ^ ((n&3)|((n>>3&1)<<2)))
        _Float16* dst = (proj == 0 ? qT : kT);
        const int h2 = lane >> 4, lml = lane & 15;
        #pragma unroll
        for (int it = 0; it < 4; ++it) {
            const int nl = it * 16 + lml;
            const int hs = (nl & 3) | (((nl >> 3) & 1) << 2);
            #pragma unroll
            for (int dc = 0; dc < 2; ++dc) {
                half8_t ch;
                #pragma unroll
                for (int e = 0; e < 8; ++e)
                    ch[e] = Tw[(w * 64 + nl) * 68 + 4 * (dc * 8 + e) + h2];
                const int chunk = (w * 2 + dc) ^ hs;
                *(half8_t*)&dst[((size_t)(b * 4 + h2) * SEQ + n0 + nl) * HDIM
                                + chunk * 8] = ch;
            }
        }
    } else {
        // v: tiles [bh][jt][d][jl], 16B chunk jc at jc^(d&7)
        const int hh = lane & 3, dl = (lane >> 2) & 15;
        const int d = w * 16 + dl;
        const size_t rowbase =
            (((size_t)(b * 4 + hh) * NJT + (n0 >> 6)) * HDIM + d) * (size_t)TM;
        #pragma unroll
        for (int jc = 0; jc < 8; ++jc) {
            half8_t ch;
            #pragma unroll
            for (int e = 0; e < 8; ++e)
                ch[e] = Tw[(w * 64 + jc * 8 + e) * 68 + 4 * dl + hh];
            *(half8_t*)&vT[rowbase + ((jc ^ (dl & 7)) << 3)] = ch;
        }
    }
}

// ---------- k2: attention, split-j, unnormalized output (round-8 exact) ----------
// grid 1024 flat; XCD-aware remap: work = (lid&7)*128 + (lid>>3).
// 4 waves x 32 rows. 16 j-tiles. QK^T with permuted K rows
// (jrow = jb*32 + rbase + 4u, rbase = 8*(lm>>2)+(lm&3)) so exp(S) registers
// form x32 A-frags; PV via mfma_16x16x32 (16/tile). Rowsum f32 VALU.
// Q pre-scaled by 0.125*log2(e) -> P = exp2(S).
__global__ __launch_bounds__(256, 4)
void attn_f16(const _Float16* __restrict__ qT, const _Float16* __restrict__ kT,
              const _Float16* __restrict__ vT, _Float16* __restrict__ xa,
              _Float16* __restrict__ xb, float* __restrict__ rs)
{
    const int lid = blockIdx.x;
    const int work = (lid & 7) * 128 + (lid >> 3);
    const int bh = work >> 5, b = bh >> 2, h = bh & 3;
    const int jh = (work >> 4) & 1;
    const int ib = work & 15;
    const int tid = threadIdx.x, wid = tid >> 6, lane = tid & 63;
    const int lm = lane & 15, g = lane >> 4;
    const int i0 = ib * TN + wid * 32;

    __shared__ _Float16 Kb[2][TM * HDIM];   // 8 KB each
    __shared__ _Float16 Vb[2][TM * HDIM];

    const int hq = (lm & 3) | (((lm >> 3) & 1) << 2);  // Q-row hash (row%16=lm)
    const int hk = (lm & 3) | (((lm >> 2) & 1) << 2);  // permuted K-row hash
    const int rbase = 8 * (lm >> 2) + (lm & 3);        // K row permutation

    // Q B-frags (scale pre-folded)
    half8_t bq[2][2];
    const _Float16* qbase = qT + (size_t)bh * SEQ * HDIM;
    #pragma unroll
    for (int rt = 0; rt < 2; ++rt)
        #pragma unroll
        for (int kd = 0; kd < 2; ++kd) {
            const int row = i0 + rt * 16 + lm;
            bq[rt][kd] = *(const half8_t*)(qbase + (size_t)row * HDIM
                                           + (((kd * 4 + g) ^ hq) << 3));
        }

    const char* kt = (const char*)(kT + ((size_t)bh * SEQ + jh * (SEQ / 2)) * HDIM);
    const char* vt = (const char*)(vT + ((size_t)bh * NJT + jh * 16) * TM * HDIM);

    float4_t o[2][4];
    float rsum[2][2] = {{0.f, 0.f}, {0.f, 0.f}};   // [jb][rt]
    #pragma unroll
    for (int rt = 0; rt < 2; ++rt)
        #pragma unroll
        for (int dt = 0; dt < 4; ++dt) o[rt][dt] = (float4_t){0.f, 0.f, 0.f, 0.f};

    #define STAGE(jt, bu)                                                     \
        {                                                                     \
            const char* kg = kt + (size_t)(jt) * 8192;                        \
            const char* vg = vt + (size_t)(jt) * 8192;                        \
            _Pragma("unroll")                                                 \
            for (int p = 0; p < 2; ++p) {                                     \
                const int c = wid + p * 4;                                    \
                ld16_lds(kg + c * 1024 + lane * 16, (char*)&Kb[bu][0] + c * 1024); \
                ld16_lds(vg + c * 1024 + lane * 16, (char*)&Vb[bu][0] + c * 1024); \
            }                                                                 \
        }

    STAGE(0, 0);
    __syncthreads();

    for (int jt = 0; jt < 16; ++jt) {
        const int cur = jt & 1;
        if (jt + 1 < 16) STAGE(jt + 1, cur ^ 1);

        // S^T = K·Q^T with permuted K rows: s[jb][u][rt], lane g reg r holds
        // S^T[j = jb*32 + 8g + 4u + r][i = rt*16 + lm]
        float4_t s[2][2][2];
        #pragma unroll
        for (int jb = 0; jb < 2; ++jb)
            #pragma unroll
            for (int u = 0; u < 2; ++u)
                #pragma unroll
                for (int rt = 0; rt < 2; ++rt)
                    s[jb][u][rt] = (float4_t){0.f, 0.f, 0.f, 0.f};
        #pragma unroll
        for (int kd = 0; kd < 2; ++kd)
            #pragma unroll
            for (int jb = 0; jb < 2; ++jb)
                #pragma unroll
                for (int u = 0; u < 2; ++u) {
                    const int jrow = jb * 32 + rbase + 4 * u;
                    const half8_t fk = *(const half8_t*)
                        &Kb[cur][jrow * HDIM + (((kd * 4 + g) ^ hk) << 3)];
                    #pragma unroll
                    for (int rt = 0; rt < 2; ++rt)
                        s[jb][u][rt] = __builtin_amdgcn_mfma_f32_16x16x32_f16(
                            fk, bq[rt][kd], s[jb][u][rt], 0, 0, 0);
                }

        // P = exp2(S); pack u=0 -> e0..3, u=1 -> e4..7 (j = 8g+e per lane)
        half8_t ap[2][2];
        #pragma unroll
        for (int jb = 0; jb < 2; ++jb)
            #pragma unroll
            for (int rt = 0; rt < 2; ++rt) {
                half8_t p;
                #pragma unroll
                for (int r = 0; r < 4; ++r) {
                    const float e0 = __builtin_amdgcn_exp2f(s[jb][0][rt][r]);
                    const float e1 = __builtin_amdgcn_exp2f(s[jb][1][rt][r]);
                    rsum[jb][rt] += e0;
                    rsum[jb][rt] += e1;
                    p[r]     = (_Float16)e0;
                    p[r + 4] = (_Float16)e1;
                }
                ap[jb][rt] = p;
            }

        // O += P·V, x32 MFMA, V as b128 reads (chunk (jb*4+g)^(lm&7))
        #pragma unroll
        for (int jb = 0; jb < 2; ++jb)
            #pragma unroll
            for (int dt = 0; dt < 4; ++dt) {
                const int d = dt * 16 + lm;
                const half8_t fv = *(const half8_t*)
                    &Vb[cur][d * TM + (((jb * 4 + g) ^ (lm & 7)) << 3)];
                #pragma unroll
                for (int rt = 0; rt < 2; ++rt)
                    o[rt][dt] = __builtin_amdgcn_mfma_f32_16x16x32_f16(
                        ap[jb][rt], fv, o[rt][dt], 0, 0, 0);
            }
        __syncthreads();
    }

    // epilogue: unnormalized O -> xp[b][n][c]; rowsum reduce -> rs[jh][bh][n]
    _Float16* xp = jh ? xb : xa;
    #pragma unroll
    for (int rt = 0; rt < 2; ++rt)
        #pragma unroll
        for (int dt = 0; dt < 4; ++dt) {
            const int c = 4 * (dt * 16 + lm) + h;
            #pragma unroll
            for (int r = 0; r < 4; ++r) {
                const int n = i0 + rt * 16 + 4 * g + r;
                xp[((size_t)b * SEQ + n) * DMODEL + c] = (_Float16)o[rt][dt][r];
            }
        }
    #pragma unroll
    for (int rt = 0; rt < 2; ++rt) {
        float v = rsum[0][rt] + rsum[1][rt];
        v += __shfl_xor(v, 16);
        v += __shfl_xor(v, 32);
        if (g == 0)
            rs[((size_t)jh * 32 + bh) * SEQ + i0 + rt * 16 + lm] = v;
    }
    #undef STAGE
}

// ---------- k3: final projection with fused combine/normalize ----------
// NEW: (xa+xb) staged ONCE per block into 32KB LDS (XOR-swizzled b128 rows,
// one barrier) instead of each wave re-reading the full panel from global.
// A-frags read Wm fp32 directly (cvt in-register). pm multiply on B-frags.
__global__ __launch_bounds__(256)
void gemm_final(const float* __restrict__ Wm, const float* __restrict__ bias,
                const _Float16* __restrict__ xa, const _Float16* __restrict__ xb,
                const float* __restrict__ rs, float* __restrict__ out)
{
    const int n0 = blockIdx.x * 64, m0 = blockIdx.y * 128;
    const int b = blockIdx.z;
    const int tid = threadIdx.x, w = tid >> 6, lane = tid & 63;
    const int lm = lane & 15, g = lane >> 4, g8 = g * 8;
    const int cw0 = m0 + w * 32;

    __shared__ _Float16 Xc[64 * DMODEL];   // 32 KB [n][c], chunk c8 at c8^(n&7)

    // ---- stage (xa+xb) -> LDS, coalesced 512B rows, swizzled chunks ----
    {
        const int c8 = tid & 31, nb = tid >> 5;   // chunk, row-group
        const _Float16* Pa = xa + ((size_t)b * SEQ + n0) * DMODEL;
        const _Float16* Pb = xb + ((size_t)b * SEQ + n0) * DMODEL;
        #pragma unroll
        for (int j = 0; j < 8; ++j) {
            const int n = nb * 8 + j;
            const size_t off = (size_t)n * DMODEL + c8 * 8;
            const half8_t va = *(const half8_t*)&Pa[off];
            const half8_t vb = *(const half8_t*)&Pb[off];
            const half8_t sv = va + vb;
            *(half8_t*)&Xc[n * DMODEL + ((c8 ^ (n & 7)) << 3)] = sv;
        }
    }

    // per-nt packed normalizers: pm[nt][e] = 1/(rsA+rsB) for h = e&3 at n
    half8_t pm[4];
    #pragma unroll
    for (int nt = 0; nt < 4; ++nt) {
        const int n = n0 + nt * 16 + lm;
        #pragma unroll
        for (int hh = 0; hh < 4; ++hh) {
            const float l = rs[(size_t)(b * 4 + hh) * SEQ + n]
                          + rs[(size_t)(32 + b * 4 + hh) * SEQ + n];
            const _Float16 iv = (_Float16)(1.0f / l);
            pm[nt][hh] = iv; pm[nt][hh + 4] = iv;
        }
    }
    __syncthreads();

    float4_t acc[2][4];
    #pragma unroll
    for (int mt = 0; mt < 2; ++mt)
        #pragma unroll
        for (int nt = 0; nt < 4; ++nt) acc[mt][nt] = (float4_t){0.f, 0.f, 0.f, 0.f};

    #pragma unroll
    for (int k0 = 0; k0 < DMODEL; k0 += 64) {
        half8_t a[2][2], bb[4][2];
        #pragma unroll
        for (int mt = 0; mt < 2; ++mt)
            #pragma unroll
            for (int kd = 0; kd < 2; ++kd) {
                const float* wp = &Wm[(size_t)(cw0 + mt * 16 + lm) * DMODEL
                                      + k0 + kd * 32 + g8];
                a[mt][kd] = cvt8(*(const float4*)wp, *(const float4*)(wp + 4));
            }
        #pragma unroll
        for (int nt = 0; nt < 4; ++nt)
            #pragma unroll
            for (int kd = 0; kd < 2; ++kd) {
                const int n = nt * 16 + lm;
                const int c8 = (k0 >> 3) + kd * 4 + g;
                const half8_t sv = *(const half8_t*)
                    &Xc[n * DMODEL + ((c8 ^ (n & 7)) << 3)];
                bb[nt][kd] = sv * pm[nt];
            }
        #pragma unroll
        for (int kd = 0; kd < 2; ++kd)
            #pragma unroll
            for (int mt = 0; mt < 2; ++mt)
                #pragma unroll
                for (int nt = 0; nt < 4; ++nt)
                    acc[mt][nt] = __builtin_amdgcn_mfma_f32_16x16x32_f16(
                        a[mt][kd], bb[nt][kd], acc[mt][nt], 0, 0, 0);
    }

    #pragma unroll
    for (int mt = 0; mt < 2; ++mt)
        #pragma unroll
        for (int r = 0; r < 4; ++r) {
            const int co = cw0 + mt * 16 + g * 4 + r;
            const float bv_ = bias[co];
            #pragma unroll
            for (int nt = 0; nt < 4; ++nt)
                out[((size_t)b * DMODEL + co) * SEQ + n0 + nt * 16 + lm] =
                    acc[mt][nt][r] + bv_;
        }
}

extern "C" void kernel_launch(void* const* d_in, const int* in_sizes, int n_in,
                              void* d_out, int out_size, void* d_ws, size_t ws_size,
                              hipStream_t stream) {
    const float* query = (const float*)d_in[0];
    const float* key_  = (const float*)d_in[1];
    const float* value = (const float*)d_in[2];
    const float* Wq = (const float*)d_in[3];  const float* bq = (const float*)d_in[4];
    const float* Wk = (const float*)d_in[5];  const float* bk = (const float*)d_in[6];
    const float* Wv = (const float*)d_in[7];  const float* bv = (const float*)d_in[8];
    const float* Wm = (const float*)d_in[9];  const float* bm = (const float*)d_in[10];
    float* out = (float*)d_out;

    const size_t bufElems = (size_t)BATCH * DMODEL * SEQ;   // 4,194,304
    _Float16* qT = (_Float16*)d_ws;    // 8 MB [bh][n][d] swizzled
    _Float16* kT = qT + bufElems;      // 8 MB
    _Float16* vT = kT + bufElems;      // 8 MB [bh][jt][d][jl] swizzled
    _Float16* xa = vT + bufElems;      // 8 MB [b][n][c] unnormalized, j-half 0
    _Float16* xb = xa + bufElems;      // 8 MB j-half 1
    float*    rsb = (float*)(xb + bufElems);  // 512 KB rowsums [2][32][2048]

    gemm_qkv<<<dim3(SEQ / 64, 3 * BATCH), 256, 0, stream>>>(
        Wq, Wk, Wv, bq, bk, bv, query, key_, value, qT, kT, vT);
    attn_f16<<<dim3(1024), 256, 0, stream>>>(qT, kT, vT, xa, xb, rsb);
    gemm_final<<<dim3(SEQ / 64, 2, BATCH), 256, 0, stream>>>(
        Wm, bm, xa, xb, rsb, out);
}

// Round 5
// 175.299 us; speedup vs baseline: 1.1978x; 1.0591x over previous
//
#include <hip/hip_runtime.h>
#include <math.h>

// MultiHeadedAttention: B=8, d_model=256, H=4, d_head=64, N=2048, fp32 I/O.
// Round 11: store-coalescing pass. (1) attn output layout [b][n][h*64+d]
// (contiguous 128B per block-row; WRITE was 2.65x amplified by 2B scatter).
// (2) gemm_final runs in hd-permuted k-order: Wm pre-permuted+cvt'd to
// wfp[co][hd] by 32 extra blocks inside gemm_qkv's grid (k-order change is
// invisible to MFMA as long as A,B agree); pm becomes per-frag scalar.
// (3) gemm_qkv epilogues remapped so each wave-store is 8x128B contiguous
// rows (was 64 scattered 16B pieces per instruction).
// Channel trap: reshape(b,64,4,N) => c = 4*d + h (heads fast).

constexpr int BATCH  = 8;
constexpr int DMODEL = 256;
constexpr int SEQ    = 2048;
constexpr int HDIM   = 64;
constexpr int TN     = 128;        // attn q rows per block (32/wave)
constexpr int TM     = 64;         // attn j per tile
constexpr int NJT    = SEQ / TM;   // 32

typedef _Float16 half2_t __attribute__((ext_vector_type(2)));
typedef _Float16 half4_t __attribute__((ext_vector_type(4)));
typedef _Float16 half8_t __attribute__((ext_vector_type(8)));
typedef float    float4_t __attribute__((ext_vector_type(4)));

static __device__ __forceinline__ void ld16_lds(const void* g, void* l) {
    __builtin_amdgcn_global_load_lds(
        (const __attribute__((address_space(1))) unsigned*)g,
        (__attribute__((address_space(3))) unsigned*)l, 16, 0, 0);
}

// fp32x8 -> half8 (RNE)
static __device__ __forceinline__ half8_t cvt8(const float4 w0, const float4 w1) {
    half8_t a;
    a[0] = (_Float16)w0.x; a[1] = (_Float16)w0.y;
    a[2] = (_Float16)w0.z; a[3] = (_Float16)w0.w;
    a[4] = (_Float16)w1.x; a[5] = (_Float16)w1.y;
    a[6] = (_Float16)w1.z; a[7] = (_Float16)w1.w;
    return a;
}

// ---------- k1: fused transpose + QKV projection (+ Wm permute blocks) ----------
// grid (SEQ/64=32, 25): y<24 -> proj GEMM (proj = y>>3, b = y&7);
// y==24 -> 32 blocks permute+cvt Wm fp32 [co][4d+h] -> wfp f16 [co][hd].
// Stage A: X[b,c,n] fp32 -> LDS Xs[n][c] f16. Stage B: MFMA, W fp32 cvt'd
// in-register. Epilogues (wave-remapped, 1KB-contiguous stores):
// q/k -> [bh][n][d-chunks swizzled], v -> 8KB j-tiles [bh][jt][d][jl].
// Q gets * 0.125*log2(e) folded in.
__global__ __launch_bounds__(256, 3)
void gemm_qkv(const float* __restrict__ Wq, const float* __restrict__ Wk,
              const float* __restrict__ Wv, const float* __restrict__ Wm,
              const float* __restrict__ bq, const float* __restrict__ bk,
              const float* __restrict__ bv,
              const float* __restrict__ Xq, const float* __restrict__ Xk,
              const float* __restrict__ Xv, _Float16* __restrict__ qT,
              _Float16* __restrict__ kT, _Float16* __restrict__ vT,
              _Float16* __restrict__ wfp)
{
    if (blockIdx.y == 24) {
        // Wm permute: wfp[co][hd] = (f16)Wm[co][4*(hd&63) + (hd>>6)]
        const int r = blockIdx.x * 8 + (threadIdx.x >> 5);   // co row
        const int c32 = threadIdx.x & 31;
        half8_t o8;
        #pragma unroll
        for (int e = 0; e < 8; ++e) {
            const int hd = c32 * 8 + e;
            o8[e] = (_Float16)Wm[r * DMODEL + 4 * (hd & 63) + (hd >> 6)];
        }
        *(half8_t*)&wfp[(size_t)r * DMODEL + c32 * 8] = o8;
        return;
    }

    const int n0 = blockIdx.x * 64;
    const int proj = blockIdx.y >> 3, b = blockIdx.y & 7;
    const float* W    = proj == 0 ? Wq : proj == 1 ? Wk : Wv;   // fp32 [co][ci]
    const float* bias = proj == 0 ? bq : proj == 1 ? bk : bv;
    const float* X    = (proj == 0 ? Xq : proj == 1 ? Xk : Xv)
                        + (size_t)b * DMODEL * SEQ;
    // fold attention scale (1/8) and log2(e) into Q so attn uses exp2 directly
    const float qs = (proj == 0) ? 0.18033688011112042f : 1.0f;

    __shared__ __align__(16) char lds[50432];
    float*    T  = (float*)lds;               // [64][65] fp32 (stage A scratch)
    _Float16* Xs = (_Float16*)(lds + 16640);  // [64][264] f16
    _Float16* Tw = (_Float16*)lds;            // [4][64][68] f16 (epilogue, aliases)

    const int tid = threadIdx.x, tn = tid & 15, tc = tid >> 4;

    // ---- Stage A: transpose+cvt 256ci x 64n ----
    #pragma unroll
    for (int cc = 0; cc < 4; ++cc) {
        __syncthreads();
        #pragma unroll
        for (int i = 0; i < 4; ++i) {
            const int c = tc + 16 * i;
            const float4 v = *(const float4*)&X[(size_t)(cc * 64 + c) * SEQ + n0 + tn * 4];
            T[c * 65 + tn * 4 + 0] = v.x; T[c * 65 + tn * 4 + 1] = v.y;
            T[c * 65 + tn * 4 + 2] = v.z; T[c * 65 + tn * 4 + 3] = v.w;
        }
        __syncthreads();
        #pragma unroll
        for (int i = 0; i < 4; ++i) {
            const int n = tc + 16 * i;
            half4_t h4;
            #pragma unroll
            for (int j = 0; j < 4; ++j) h4[j] = (_Float16)T[(tn * 4 + j) * 65 + n];
            *(half4_t*)&Xs[n * 264 + cc * 64 + tn * 4] = h4;
        }
    }
    __syncthreads();

    // ---- Stage B: MFMA GEMM ----
    const int w = tid >> 6, lane = tid & 63;
    const int lm = lane & 15, g = lane >> 4, g8 = g * 8;
    const int cw0 = w * 64;

    float4_t acc[4][4];
    #pragma unroll
    for (int mt = 0; mt < 4; ++mt)
        #pragma unroll
        for (int nt = 0; nt < 4; ++nt) acc[mt][nt] = (float4_t){0.f, 0.f, 0.f, 0.f};

    #pragma unroll
    for (int k0 = 0; k0 < DMODEL; k0 += 64) {
        half8_t a[4][2], bb[4][2];
        #pragma unroll
        for (int mt = 0; mt < 4; ++mt)
            #pragma unroll
            for (int kd = 0; kd < 2; ++kd) {
                const float* wp = &W[(size_t)(cw0 + mt * 16 + lm) * DMODEL
                                     + k0 + kd * 32 + g8];
                a[mt][kd] = cvt8(*(const float4*)wp, *(const float4*)(wp + 4));
            }
        #pragma unroll
        for (int nt = 0; nt < 4; ++nt)
            #pragma unroll
            for (int kd = 0; kd < 2; ++kd)
                bb[nt][kd] = *(const half8_t*)&Xs[(nt * 16 + lm) * 264
                                                  + k0 + kd * 32 + g8];
        #pragma unroll
        for (int kd = 0; kd < 2; ++kd)
            #pragma unroll
            for (int mt = 0; mt < 4; ++mt)
                #pragma unroll
                for (int nt = 0; nt < 4; ++nt)
                    acc[mt][nt] = __builtin_amdgcn_mfma_f32_16x16x32_f16(
                        a[mt][kd], bb[nt][kd], acc[mt][nt], 0, 0, 0);
    }
    __syncthreads();   // Xs dead; Tw may now alias it

    // wave-private transpose: Tw[w][n_local][co_local]  (Tw[w][nl][col] = D[w*64+col][nl])
    #pragma unroll
    for (int mt = 0; mt < 4; ++mt) {
        const float4 b4 = *(const float4*)&bias[cw0 + mt * 16 + g * 4];
        const float bb4[4] = {b4.x, b4.y, b4.z, b4.w};
        #pragma unroll
        for (int nt = 0; nt < 4; ++nt) {
            half4_t pk;
            #pragma unroll
            for (int r = 0; r < 4; ++r)
                pk[r] = (_Float16)((acc[mt][nt][r] + bb4[r]) * qs);
            *(half4_t*)&Tw[((w * 64 + nt * 16 + lm)) * 68 + mt * 16 + g * 4] = pk;
        }
    }
    __syncthreads();   // epilogue reads cross-wave

    if (proj < 2) {
        // q/k: wave w -> head h=w. Lane: row nl = it*8+(l>>3), d-chunk dcg=l&7.
        // Store 16B at chunk dcg^hs(nl): 8 lanes fill a 128B row, 8 rows/instr
        // -> 1KB contiguous per wave-store.
        _Float16* dst = (proj == 0 ? qT : kT);
        const int h = w;
        const int dcg = lane & 7, nlb = lane >> 3;
        #pragma unroll
        for (int it = 0; it < 8; ++it) {
            const int nl = it * 8 + nlb;
            const int hs = (nl & 3) | (((nl >> 3) & 1) << 2);
            half8_t ch;
            #pragma unroll
            for (int e = 0; e < 8; ++e) {
                // value D[co=4*(dcg*8+e)+h][nl]
                ch[e] = Tw[((dcg >> 1) * 64 + nl) * 68
                           + 4 * ((dcg & 1) * 8 + e) + h];
            }
            const int chunk = dcg ^ hs;
            *(half8_t*)&dst[((size_t)(b * 4 + h) * SEQ + n0 + nl) * HDIM
                            + chunk * 8] = ch;
        }
    } else {
        // v: wave w -> head h=w. Lane: d = it*8+(l>>3), j-chunk jc=l&7.
        // tiles [bh][jt][d][jl], 16B chunk jc at jc^(d&7); 8 d-rows/instr.
        const int h = w;
        const int jc = lane & 7, db = lane >> 3;
        const size_t tilebase =
            (((size_t)(b * 4 + h) * NJT + (n0 >> 6)) * HDIM) * (size_t)TM;
        #pragma unroll
        for (int it = 0; it < 8; ++it) {
            const int d = it * 8 + db;
            half8_t ch;
            #pragma unroll
            for (int e = 0; e < 8; ++e) {
                // value D[co=4d+h][j = jc*8+e]
                ch[e] = Tw[((d >> 4) * 64 + jc * 8 + e) * 68
                           + 4 * (d & 15) + h];
            }
            *(half8_t*)&vT[tilebase + (size_t)d * TM + ((jc ^ (d & 7)) << 3)] = ch;
        }
    }
}

// ---------- k2: attention, split-j, unnormalized output ----------
// grid 1024 flat; XCD-aware remap: work = (lid&7)*128 + (lid>>3).
// 4 waves x 32 rows. 16 j-tiles. QK^T with permuted K rows
// (jrow = jb*32 + rbase + 4u) so exp(S) registers form x32 A-frags; PV via
// mfma_16x16x32. Rowsum f32 VALU. Q pre-scaled by 0.125*log2(e) -> exp2.
// Output layout now [b][n][h*64+d]: block's 128B sub-row contiguous.
__global__ __launch_bounds__(256, 4)
void attn_f16(const _Float16* __restrict__ qT, const _Float16* __restrict__ kT,
              const _Float16* __restrict__ vT, _Float16* __restrict__ xa,
              _Float16* __restrict__ xb, float* __restrict__ rs)
{
    const int lid = blockIdx.x;
    const int work = (lid & 7) * 128 + (lid >> 3);
    const int bh = work >> 5, b = bh >> 2, h = bh & 3;
    const int jh = (work >> 4) & 1;
    const int ib = work & 15;
    const int tid = threadIdx.x, wid = tid >> 6, lane = tid & 63;
    const int lm = lane & 15, g = lane >> 4;
    const int i0 = ib * TN + wid * 32;

    __shared__ _Float16 Kb[2][TM * HDIM];   // 8 KB each
    __shared__ _Float16 Vb[2][TM * HDIM];

    const int hq = (lm & 3) | (((lm >> 3) & 1) << 2);  // Q-row hash (row%16=lm)
    const int hk = (lm & 3) | (((lm >> 2) & 1) << 2);  // permuted K-row hash
    const int rbase = 8 * (lm >> 2) + (lm & 3);        // K row permutation

    // Q B-frags (scale pre-folded)
    half8_t bq[2][2];
    const _Float16* qbase = qT + (size_t)bh * SEQ * HDIM;
    #pragma unroll
    for (int rt = 0; rt < 2; ++rt)
        #pragma unroll
        for (int kd = 0; kd < 2; ++kd) {
            const int row = i0 + rt * 16 + lm;
            bq[rt][kd] = *(const half8_t*)(qbase + (size_t)row * HDIM
                                           + (((kd * 4 + g) ^ hq) << 3));
        }

    const char* kt = (const char*)(kT + ((size_t)bh * SEQ + jh * (SEQ / 2)) * HDIM);
    const char* vt = (const char*)(vT + ((size_t)bh * NJT + jh * 16) * TM * HDIM);

    float4_t o[2][4];
    float rsum[2][2] = {{0.f, 0.f}, {0.f, 0.f}};   // [jb][rt]
    #pragma unroll
    for (int rt = 0; rt < 2; ++rt)
        #pragma unroll
        for (int dt = 0; dt < 4; ++dt) o[rt][dt] = (float4_t){0.f, 0.f, 0.f, 0.f};

    #define STAGE(jt, bu)                                                     \
        {                                                                     \
            const char* kg = kt + (size_t)(jt) * 8192;                        \
            const char* vg = vt + (size_t)(jt) * 8192;                        \
            _Pragma("unroll")                                                 \
            for (int p = 0; p < 2; ++p) {                                     \
                const int c = wid + p * 4;                                    \
                ld16_lds(kg + c * 1024 + lane * 16, (char*)&Kb[bu][0] + c * 1024); \
                ld16_lds(vg + c * 1024 + lane * 16, (char*)&Vb[bu][0] + c * 1024); \
            }                                                                 \
        }

    STAGE(0, 0);
    __syncthreads();

    for (int jt = 0; jt < 16; ++jt) {
        const int cur = jt & 1;
        if (jt + 1 < 16) STAGE(jt + 1, cur ^ 1);

        // S^T = K·Q^T with permuted K rows: s[jb][u][rt], lane g reg r holds
        // S^T[j = jb*32 + 8g + 4u + r][i = rt*16 + lm]
        float4_t s[2][2][2];
        #pragma unroll
        for (int jb = 0; jb < 2; ++jb)
            #pragma unroll
            for (int u = 0; u < 2; ++u)
                #pragma unroll
                for (int rt = 0; rt < 2; ++rt)
                    s[jb][u][rt] = (float4_t){0.f, 0.f, 0.f, 0.f};
        #pragma unroll
        for (int kd = 0; kd < 2; ++kd)
            #pragma unroll
            for (int jb = 0; jb < 2; ++jb)
                #pragma unroll
                for (int u = 0; u < 2; ++u) {
                    const int jrow = jb * 32 + rbase + 4 * u;
                    const half8_t fk = *(const half8_t*)
                        &Kb[cur][jrow * HDIM + (((kd * 4 + g) ^ hk) << 3)];
                    #pragma unroll
                    for (int rt = 0; rt < 2; ++rt)
                        s[jb][u][rt] = __builtin_amdgcn_mfma_f32_16x16x32_f16(
                            fk, bq[rt][kd], s[jb][u][rt], 0, 0, 0);
                }

        // P = exp2(S); pack u=0 -> e0..3, u=1 -> e4..7 (j = 8g+e per lane)
        half8_t ap[2][2];
        #pragma unroll
        for (int jb = 0; jb < 2; ++jb)
            #pragma unroll
            for (int rt = 0; rt < 2; ++rt) {
                half8_t p;
                #pragma unroll
                for (int r = 0; r < 4; ++r) {
                    const float e0 = __builtin_amdgcn_exp2f(s[jb][0][rt][r]);
                    const float e1 = __builtin_amdgcn_exp2f(s[jb][1][rt][r]);
                    rsum[jb][rt] += e0;
                    rsum[jb][rt] += e1;
                    p[r]     = (_Float16)e0;
                    p[r + 4] = (_Float16)e1;
                }
                ap[jb][rt] = p;
            }

        // O += P·V, x32 MFMA, V as b128 reads (chunk (jb*4+g)^(lm&7))
        #pragma unroll
        for (int jb = 0; jb < 2; ++jb)
            #pragma unroll
            for (int dt = 0; dt < 4; ++dt) {
                const int d = dt * 16 + lm;
                const half8_t fv = *(const half8_t*)
                    &Vb[cur][d * TM + (((jb * 4 + g) ^ (lm & 7)) << 3)];
                #pragma unroll
                for (int rt = 0; rt < 2; ++rt)
                    o[rt][dt] = __builtin_amdgcn_mfma_f32_16x16x32_f16(
                        ap[jb][rt], fv, o[rt][dt], 0, 0, 0);
            }
        __syncthreads();
    }

    // epilogue: unnormalized O -> xp[b][n][h*64+d]; rowsum -> rs[jh][bh][n]
    _Float16* xp = jh ? xb : xa;
    #pragma unroll
    for (int rt = 0; rt < 2; ++rt)
        #pragma unroll
        for (int dt = 0; dt < 4; ++dt) {
            const int d = dt * 16 + lm;
            #pragma unroll
            for (int r = 0; r < 4; ++r) {
                const int n = i0 + rt * 16 + 4 * g + r;
                xp[((size_t)b * SEQ + n) * DMODEL + h * HDIM + d] =
                    (_Float16)o[rt][dt][r];
            }
        }
    #pragma unroll
    for (int rt = 0; rt < 2; ++rt) {
        float v = rsum[0][rt] + rsum[1][rt];
        v += __shfl_xor(v, 16);
        v += __shfl_xor(v, 32);
        if (g == 0)
            rs[((size_t)jh * 32 + bh) * SEQ + i0 + rt * 16 + lm] = v;
    }
    #undef STAGE
}

// ---------- k3: final projection, hd-permuted k-order ----------
// A = wfp[co][hd] (f16, b128); B = (xa+xb)[n][hd] staged once to LDS
// (identical code to [n][c] — only the k semantics changed). Head is
// uniform within each half8 -> pm is a per-frag scalar splat.
__global__ __launch_bounds__(256)
void gemm_final(const _Float16* __restrict__ wfp, const float* __restrict__ bias,
                const _Float16* __restrict__ xa, const _Float16* __restrict__ xb,
                const float* __restrict__ rs, float* __restrict__ out)
{
    const int n0 = blockIdx.x * 64, m0 = blockIdx.y * 128;
    const int b = blockIdx.z;
    const int tid = threadIdx.x, w = tid >> 6, lane = tid & 63;
    const int lm = lane & 15, g = lane >> 4, g8 = g * 8;
    const int cw0 = m0 + w * 32;

    __shared__ _Float16 Xc[64 * DMODEL];   // 32 KB [n][hd], chunk c8 at c8^(n&7)

    // ---- stage (xa+xb) -> LDS, coalesced 512B rows, swizzled chunks ----
    {
        const int c8 = tid & 31, nb = tid >> 5;   // chunk, row-group
        const _Float16* Pa = xa + ((size_t)b * SEQ + n0) * DMODEL;
        const _Float16* Pb = xb + ((size_t)b * SEQ + n0) * DMODEL;
        #pragma unroll
        for (int j = 0; j < 8; ++j) {
            const int n = nb * 8 + j;
            const size_t off = (size_t)n * DMODEL + c8 * 8;
            const half8_t va = *(const half8_t*)&Pa[off];
            const half8_t vb = *(const half8_t*)&Pb[off];
            const half8_t sv = va + vb;
            *(half8_t*)&Xc[n * DMODEL + ((c8 ^ (n & 7)) << 3)] = sv;
        }
    }

    // per-(nt,h) scalar normalizers: 1/(rsA+rsB)
    _Float16 pmh[4][4];
    #pragma unroll
    for (int nt = 0; nt < 4; ++nt) {
        const int n = n0 + nt * 16 + lm;
        #pragma unroll
        for (int hh = 0; hh < 4; ++hh) {
            const float l = rs[(size_t)(b * 4 + hh) * SEQ + n]
                          + rs[(size_t)(32 + b * 4 + hh) * SEQ + n];
            pmh[nt][hh] = (_Float16)(1.0f / l);
        }
    }
    __syncthreads();

    float4_t acc[2][4];
    #pragma unroll
    for (int mt = 0; mt < 2; ++mt)
        #pragma unroll
        for (int nt = 0; nt < 4; ++nt) acc[mt][nt] = (float4_t){0.f, 0.f, 0.f, 0.f};

    #pragma unroll
    for (int k0 = 0; k0 < DMODEL; k0 += 64) {
        half8_t a[2][2], bb[4][2];
        #pragma unroll
        for (int mt = 0; mt < 2; ++mt)
            #pragma unroll
            for (int kd = 0; kd < 2; ++kd)
                a[mt][kd] = *(const half8_t*)&wfp[(size_t)(cw0 + mt * 16 + lm) * DMODEL
                                                  + k0 + kd * 32 + g8];
        #pragma unroll
        for (int nt = 0; nt < 4; ++nt)
            #pragma unroll
            for (int kd = 0; kd < 2; ++kd) {
                const int n = nt * 16 + lm;
                const int c8 = (k0 >> 3) + kd * 4 + g;
                const half8_t sv = *(const half8_t*)
                    &Xc[n * DMODEL + ((c8 ^ (n & 7)) << 3)];
                const int hh = (k0 + kd * 32 + g8) >> 6;   // uniform per frag
                bb[nt][kd] = sv * pmh[nt][hh];
            }
        #pragma unroll
        for (int kd = 0; kd < 2; ++kd)
            #pragma unroll
            for (int mt = 0; mt < 2; ++mt)
                #pragma unroll
                for (int nt = 0; nt < 4; ++nt)
                    acc[mt][nt] = __builtin_amdgcn_mfma_f32_16x16x32_f16(
                        a[mt][kd], bb[nt][kd], acc[mt][nt], 0, 0, 0);
    }

    #pragma unroll
    for (int mt = 0; mt < 2; ++mt)
        #pragma unroll
        for (int r = 0; r < 4; ++r) {
            const int co = cw0 + mt * 16 + g * 4 + r;
            const float bv_ = bias[co];
            #pragma unroll
            for (int nt = 0; nt < 4; ++nt)
                out[((size_t)b * DMODEL + co) * SEQ + n0 + nt * 16 + lm] =
                    acc[mt][nt][r] + bv_;
        }
}

extern "C" void kernel_launch(void* const* d_in, const int* in_sizes, int n_in,
                              void* d_out, int out_size, void* d_ws, size_t ws_size,
                              hipStream_t stream) {
    const float* query = (const float*)d_in[0];
    const float* key_  = (const float*)d_in[1];
    const float* value = (const float*)d_in[2];
    const float* Wq = (const float*)d_in[3];  const float* bq = (const float*)d_in[4];
    const float* Wk = (const float*)d_in[5];  const float* bk = (const float*)d_in[6];
    const float* Wv = (const float*)d_in[7];  const float* bv = (const float*)d_in[8];
    const float* Wm = (const float*)d_in[9];  const float* bm = (const float*)d_in[10];
    float* out = (float*)d_out;

    const size_t bufElems = (size_t)BATCH * DMODEL * SEQ;   // 4,194,304
    _Float16* qT = (_Float16*)d_ws;    // 8 MB [bh][n][d] swizzled
    _Float16* kT = qT + bufElems;      // 8 MB
    _Float16* vT = kT + bufElems;      // 8 MB [bh][jt][d][jl] swizzled
    _Float16* xa = vT + bufElems;      // 8 MB [b][n][hd] unnormalized, j-half 0
    _Float16* xb = xa + bufElems;      // 8 MB j-half 1
    float*    rsb = (float*)(xb + bufElems);       // 512 KB rowsums [2][32][2048]
    _Float16* wfp = (_Float16*)(rsb + 2 * 32 * SEQ);  // 128 KB Wm f16 [co][hd]

    gemm_qkv<<<dim3(SEQ / 64, 25), 256, 0, stream>>>(
        Wq, Wk, Wv, Wm, bq, bk, bv, query, key_, value, qT, kT, vT, wfp);
    attn_f16<<<dim3(1024), 256, 0, stream>>>(qT, kT, vT, xa, xb, rsb);
    gemm_final<<<dim3(SEQ / 64, 2, BATCH), 256, 0, stream>>>(
        wfp, bm, xa, xb, rsb, out);
}